// Round 5
// baseline (232.029 us; speedup 1.0000x reference)
//
#include <hip/hip_runtime.h>
#include <hip/hip_bf16.h>

// ROI Align (FPN, 4 levels, PH=PW=7, SR=2). All-fp32 I/O (verified R4 PASS).
// R5 optimization: latency-bound gather -> raise memory-level parallelism.
//  - CPT=4 channels per thread: coordinate/weight math amortized 4x, and
//    64 independent gathers per thread fully unrolled (was 16, serialized
//    by a 16-VGPR allocation and divergent `continue` blocks).
//  - Branch-free validity: weights pre-multiplied by (valid ? 0.25 : 0),
//    indices always clamped in-bounds -> no divergence, no fault.

#define NUM_CH 256
#define CPT 4
#define CGRP (NUM_CH / CPT)   // 64 channel-groups

__global__ __launch_bounds__(256) void roi_align_kernel(
    const float* __restrict__ f0,
    const float* __restrict__ f1,
    const float* __restrict__ f2,
    const float* __restrict__ f3,
    const float* __restrict__ rois_f,
    const int* __restrict__ level,
    float* __restrict__ out,
    int total_threads)
{
    int e = blockIdx.x * blockDim.x + threadIdx.x;
    if (e >= total_threads) return;

    int p  = e % 49;            // output pixel (lane-major: coalesced-ish)
    int t  = e / 49;
    int cg = t % CGRP;          // channel group (4 channels)
    int k  = t / CGRP;          // roi
    int ph = p / 7;
    int pw = p % 7;

    int lvl = level[k];
    const float* f;
    int H, W;
    float scale;
    if (lvl == 0)      { f = f0; H = 200; W = 200; scale = 0.25f;    }
    else if (lvl == 1) { f = f1; H = 100; W = 100; scale = 0.125f;   }
    else if (lvl == 2) { f = f2; H = 50;  W = 50;  scale = 0.0625f;  }
    else               { f = f3; H = 25;  W = 25;  scale = 0.03125f; }

    // rois: fp32 (verified); keep adaptive fallback as cheap insurance.
    const float* rf = rois_f + (size_t)k * 5;
    float r0 = rf[0];
    float x1, y1, x2, y2;
    if (r0 == 0.0f || r0 == 1.0f) {
        x1 = rf[1]; y1 = rf[2]; x2 = rf[3]; y2 = rf[4];
    } else {
        const __hip_bfloat16* rb = (const __hip_bfloat16*)rois_f + (size_t)k * 5;
        r0 = __bfloat162float(rb[0]);
        x1 = __bfloat162float(rb[1]);
        y1 = __bfloat162float(rb[2]);
        x2 = __bfloat162float(rb[3]);
        y2 = __bfloat162float(rb[4]);
    }
    x1 *= scale; y1 *= scale; x2 *= scale; y2 *= scale;

    int b = (int)r0;
    b = (b < 0) ? 0 : ((b > 1) ? 1 : b);

    float roi_w = fmaxf(x2 - x1, 1.0f);
    float roi_h = fmaxf(y2 - y1, 1.0f);
    float bw = roi_w * (1.0f / 7.0f);
    float bh = roi_h * (1.0f / 7.0f);

    // ---- Precompute the 4 subsample positions once (shared by 4 channels) --
    int   rl[4], rh[4], cxl[4], cxh[4];         // row offsets & columns
    float w00[4], w01[4], w10[4], w11[4];       // corner weights * valid * 0.25
    #pragma unroll
    for (int s = 0; s < 4; ++s) {
        int sy = s >> 1, sx = s & 1;
        float y = y1 + (float)ph * bh + ((float)sy + 0.5f) * (bh * 0.5f);
        float x = x1 + (float)pw * bw + ((float)sx + 0.5f) * (bw * 0.5f);
        bool valid = (y > -1.0f) && (y < (float)H) && (x > -1.0f) && (x < (float)W);
        float yc = fmaxf(y, 0.0f);
        float xc = fmaxf(x, 0.0f);
        int yl = min((int)yc, H - 1);
        int yh = min(yl + 1, H - 1);
        int xl = min((int)xc, W - 1);
        int xh = min(xl + 1, W - 1);
        float ly = (yl >= H - 1) ? 0.0f : (yc - (float)yl);
        float lx = (xl >= W - 1) ? 0.0f : (xc - (float)xl);
        float hy = 1.0f - ly;
        float hx = 1.0f - lx;
        float vs = valid ? 0.25f : 0.0f;   // fold validity + 2x2 mean
        rl[s]  = yl * W;
        rh[s]  = yh * W;
        cxl[s] = xl;
        cxh[s] = xh;
        w00[s] = hy * hx * vs;
        w01[s] = hy * lx * vs;
        w10[s] = ly * hx * vs;
        w11[s] = ly * lx * vs;
    }

    // ---- 4 channels x 4 samples x 4 corners = 64 independent gathers ------
    int HW = H * W;
    int c0 = cg * CPT;
    const float* plane0 = f + ((size_t)b * NUM_CH + c0) * (size_t)HW;

    float acc[CPT];
    #pragma unroll
    for (int ci = 0; ci < CPT; ++ci) acc[ci] = 0.0f;

    #pragma unroll
    for (int ci = 0; ci < CPT; ++ci) {
        const float* pb = plane0 + (size_t)ci * HW;
        #pragma unroll
        for (int s = 0; s < 4; ++s) {
            float v00 = pb[rl[s] + cxl[s]];
            float v01 = pb[rl[s] + cxh[s]];
            float v10 = pb[rh[s] + cxl[s]];
            float v11 = pb[rh[s] + cxh[s]];
            acc[ci] += w00[s] * v00 + w01[s] * v01
                     + w10[s] * v10 + w11[s] * v11;
        }
    }

    // ---- store: out[((k*256 + c0+ci)*49) + p] ------------------------------
    size_t obase = ((size_t)k * NUM_CH + c0) * 49 + p;
    #pragma unroll
    for (int ci = 0; ci < CPT; ++ci)
        out[obase + (size_t)ci * 49] = acc[ci];
}

extern "C" void kernel_launch(void* const* d_in, const int* in_sizes, int n_in,
                              void* d_out, int out_size, void* d_ws, size_t ws_size,
                              hipStream_t stream) {
    const float* f0   = (const float*)d_in[0];
    const float* f1   = (const float*)d_in[1];
    const float* f2   = (const float*)d_in[2];
    const float* f3   = (const float*)d_in[3];
    const float* rois = (const float*)d_in[4];
    // d_in[5] = rois_counts (unused: level[] fully determines routing)
    const int* level = (const int*)d_in[6];
    float* out = (float*)d_out;

    int total_threads = (out_size / NUM_CH / 49) * CGRP * 49;  // K * 64 * 49
    int threads = 256;
    int blocks = (total_threads + threads - 1) / threads;
    roi_align_kernel<<<blocks, threads, 0, stream>>>(f0, f1, f2, f3, rois, level, out, total_threads);
}